// Round 11
// baseline (208.487 us; speedup 1.0000x reference)
//
#include <hip/hip_runtime.h>
#include <hip/hip_bf16.h>

// CACE message passing, fused. MAX_L=3 -> NL=20, N_RBF=8, RB=8, K=3 -> C=9,
// NB=5, CUTOFF=5.5, T_MP=1, MP_NORM=0.2, N=2000, E=50000. fp32 I/O.
// Round 11: edge features recomputed IN-LDS from raw inputs in both node
// kernels (fill_est) — kills k_edge + the 16MB edata array (write + 2 reads),
// the fp32 A array (k_node2 recomputes own Ab bit-identically) and B0
// (k_node2 writes both output halves). Remaining big stream: compulsory
// per-XCD fill of the 5.76MB bf16 A-mirror (measured bytes-bound wall at
// ~1.05 TB/s scattered-fetch across r3-r10; fp8 rejected: 32x quant error
// would break the 1.255 abs threshold). Gather = depth-1 register pipeline
// (r7-style; measured equal to bulk LDS staging, better occupancy).
// est row (stride 72): [0:32] gw[4][8], [32:40] fr, [40:60] ang, [60:69] enc,
// [69] send-id bits.

#define CUTF 5.5f
#define MPNORM 0.2f
#define TILE 48
#define RS 72

__constant__ int   d_DEGS[20]  = {0,1,1,1,2,2,2,2,2,2,3,3,3,3,3,3,3,3,3,3};
__constant__ float d_MULTI[20] = {1,1,1,1,1,2,2,1,2,1,1,3,3,3,6,3,1,3,3,1};

__global__ void k_count(const int* __restrict__ eidx, int* __restrict__ counts, int E) {
  int e = blockIdx.x * blockDim.x + threadIdx.x;
  if (e < E) atomicAdd(&counts[eidx[E + e]], 1);
}

// exclusive scan of counts (N<=2048, one block of 256)
__global__ void k_scan(const int* __restrict__ counts, int* __restrict__ offs, int N) {
  __shared__ int part[256];
  int t = threadIdx.x;
  int local[8]; int sum = 0;
  #pragma unroll
  for (int i = 0; i < 8; i++) {
    int idx = t*8 + i;
    int v = (idx < N) ? counts[idx] : 0;
    local[i] = sum; sum += v;
  }
  part[t] = sum; __syncthreads();
  for (int d = 1; d < 256; d <<= 1) {
    int add = (t >= d) ? part[t-d] : 0;
    __syncthreads();
    part[t] += add;
    __syncthreads();
  }
  int excl = part[t] - sum;
  #pragma unroll
  for (int i = 0; i < 8; i++) {
    int idx = t*8 + i;
    if (idx < N) offs[idx] = excl + local[i];
  }
  if (t == 255) offs[N] = part[255];
}

__global__ void k_fill(const int* __restrict__ eidx, const int* __restrict__ offs,
                       int* __restrict__ cursor, int* __restrict__ order, int E) {
  int e = blockIdx.x * blockDim.x + threadIdx.x;
  if (e >= E) return;
  int r = eidx[E + e];
  int slot = atomicAdd(&cursor[r], 1);
  order[offs[r] + slot] = e;
}

// ---- compute edge features for one CSR tile into LDS est -------------------
__device__ __forceinline__ void fill_est(
    float* est, const int* __restrict__ order, const int* __restrict__ eidx,
    const float* __restrict__ pos, const float* __restrict__ shifts,
    const int* __restrict__ species,
    const float* war_s, const float* wrad_s, const float* wemb_s,
    int tb, int cnt, int t,
    float pnx, float pny, float pnz, float er0, float er1, float er2)
{
  __syncthreads();                  // prior est consumers done
  if (t < cnt) {
    int e = order[tb + t];
    int s = eidx[e];
    float vx = pnx - pos[s*3+0] + shifts[e*3+0];
    float vy = pny - pos[s*3+1] + shifts[e*3+1];
    float vz = pnz - pos[s*3+2] + shifts[e*3+2];
    float len = sqrtf(vx*vx + vy*vy + vz*vz);
    float inv = 1.0f / (len + 1e-9f);
    float ux = vx*inv, uy = vy*inv, uz = vz*inv;
    float uu = len * (1.0f/CUTF);
    float u2 = uu*uu, u6 = u2*u2*u2;
    float fcut = (uu < 1.0f) ? (1.0f - 28.0f*u6 + 48.0f*u6*uu - 21.0f*u6*u2) : 0.0f;
    float x = 3.14159265358979f * uu;
    float sn = sinf(x), c2 = 2.0f*cosf(x), snm1 = 0.0f;
    float pref = sqrtf(2.0f/CUTF) / (len + 1e-20f);
    float* eb = est + t*RS;
    float rad[8];
    #pragma unroll
    for (int k = 0; k < 8; k++) {
      rad[k] = pref * sn;
      eb[k]  = rad[k] * fcut;             // g -> [0:8] (temp, becomes gw later)
      float nxt = c2*sn - snm1; snm1 = sn; sn = nxt;
    }
    #pragma unroll
    for (int b = 0; b < 8; b++) {         // fr = (rad @ W_ar) * fcut
      float a = 0.0f;
      #pragma unroll
      for (int k = 0; k < 8; k++) a += rad[k] * war_s[k*8+b];
      eb[32+b] = a * fcut;
    }
    float px2 = ux*ux, py2 = uy*uy, pz2 = uz*uz;
    eb[40] = 1.0f; eb[41] = ux;     eb[42] = uy;     eb[43] = uz;
    eb[44] = px2;  eb[45] = ux*uy;  eb[46] = ux*uz;  eb[47] = py2;
    eb[48] = uy*uz;eb[49] = pz2;
    eb[50] = px2*ux; eb[51] = px2*uy; eb[52] = px2*uz; eb[53] = ux*py2;
    eb[54] = ux*uy*uz; eb[55] = ux*pz2; eb[56] = py2*uy; eb[57] = py2*uz;
    eb[58] = uy*pz2; eb[59] = pz2*uz;
    int zs = species[s];
    float es0 = wemb_s[zs*3+0], es1 = wemb_s[zs*3+1], es2 = wemb_s[zs*3+2];
    eb[60] = es0*er0; eb[61] = es0*er1; eb[62] = es0*er2;
    eb[63] = es1*er0; eb[64] = es1*er1; eb[65] = es1*er2;
    eb[66] = es2*er0; eb[67] = es2*er1; eb[68] = es2*er2;
    eb[69] = __int_as_float(s);
  }
  __syncthreads();
  // gw[d][b] = sum_r g[r] * Wrad[d][r][b]  (parallel over cnt*32 items)
  int tot = cnt * 32;
  float gwv[8];
  int kq = 0;
  for (int idx = t; idx < tot; idx += 192, kq++) {
    int j = idx >> 5, f = idx & 31, d = f >> 3, b = f & 7;
    const float* gr = est + j*RS;
    float a = 0.0f;
    #pragma unroll
    for (int r = 0; r < 8; r++) a += gr[r] * wrad_s[d*64 + r*8 + b];
    gwv[kq] = a;
  }
  __syncthreads();
  kq = 0;
  for (int idx = t; idx < tot; idx += 192, kq++)
    est[(idx >> 5)*RS + (idx & 31)] = gwv[kq];
  __syncthreads();
}

// ---- phase 1: Ab (registers) -> Abf4 (bf16 mirror), chi --------------------
__global__ __launch_bounds__(192, 6) void k_nodeA(
    const float* __restrict__ pos, const float* __restrict__ shifts,
    const float* __restrict__ Wemb, const float* __restrict__ Wrad,
    const float* __restrict__ War, const float* __restrict__ Wchi,
    const int* __restrict__ species, const int* __restrict__ eidx,
    const int* __restrict__ offs, const int* __restrict__ order,
    uint4* __restrict__ Abf4, float* __restrict__ chi, int N)
{
  __shared__ float wrad_s[256];
  __shared__ float war_s[64];
  __shared__ float wchi_s[40];
  __shared__ float wemb_s[12];
  __shared__ float Bsh[360];
  __shared__ __align__(16) float est[TILE*RS];
  int t = threadIdx.x, n = blockIdx.x;
  for (int i = t; i < 256; i += 192) wrad_s[i] = Wrad[i];
  if (t < 64) war_s[t] = War[t];
  if (t < 40) wchi_s[t] = Wchi[t];
  if (t < 12) wemb_s[t] = Wemb[t];
  for (int i = t; i < 360; i += 192) Bsh[i] = 0.0f;
  int l = t / 9, c = t - l*9;
  bool act = t < 180;
  int ll = act ? l : 0, cc = act ? c : 0;
  int dgl = act ? d_DEGS[ll] : 0;
  float mlt = act ? d_MULTI[ll] : 0.0f;
  float pnx = pos[n*3+0], pny = pos[n*3+1], pnz = pos[n*3+2];
  int zr = species[n];
  __syncthreads();                 // wemb_s ready
  float er0 = wemb_s[zr*3+0], er1 = wemb_s[zr*3+1], er2 = wemb_s[zr*3+2];
  int start = offs[n], end = offs[n+1];
  float Ab[8] = {0,0,0,0,0,0,0,0};
  for (int tb = start; tb < end; tb += TILE) {
    int cnt = min(TILE, end - tb);
    fill_est(est, order, eidx, pos, shifts, species, war_s, wrad_s, wemb_s,
             tb, cnt, t, pnx, pny, pnz, er0, er1, er2);
    #pragma unroll 2
    for (int j = 0; j < cnt; j++) {
      const float* eb = est + j*RS;
      float p = eb[40+ll] * eb[60+cc];
      const float4* gw4 = reinterpret_cast<const float4*>(eb + dgl*8);
      float4 g0 = gw4[0], g1 = gw4[1];
      Ab[0] += p*g0.x; Ab[1] += p*g0.y; Ab[2] += p*g0.z; Ab[3] += p*g0.w;
      Ab[4] += p*g1.x; Ab[5] += p*g1.y; Ab[6] += p*g1.z; Ab[7] += p*g1.w;
    }
  }
  __syncthreads();     // Bsh zeros visible (also 0-edge nodes)
  if (act) {
    unsigned int pr[4];
    #pragma unroll
    for (int bp = 0; bp < 4; bp++) {
      __hip_bfloat16 blo = __float2bfloat16(Ab[2*bp]);
      __hip_bfloat16 bhi = __float2bfloat16(Ab[2*bp+1]);
      pr[bp] = (unsigned int)(*reinterpret_cast<unsigned short*>(&blo))
             | ((unsigned int)(*reinterpret_cast<unsigned short*>(&bhi)) << 16);
    }
    uint4 pk; pk.x = pr[0]; pk.y = pr[1]; pk.z = pr[2]; pk.w = pr[3];
    Abf4[(size_t)n*180 + t] = pk;
    if (l == 0) {
      #pragma unroll
      for (int b = 0; b < 8; b++) Bsh[b*45 + c] = Ab[b];
    }
    int kk = 1 + dgl;
    #pragma unroll
    for (int b = 0; b < 8; b++) atomicAdd(&Bsh[b*45 + kk*9 + c], mlt*Ab[b]*Ab[b]);
  }
  __syncthreads();
  if (t < 9) {
    float s = 0.0f;
    for (int b = 0; b < 8; b++)
      #pragma unroll
      for (int kq = 0; kq < 5; kq++) s += Bsh[b*45 + kq*9 + t] * wchi_s[b*5 + kq];
    chi[n*9 + t] = s;
  }
}

// ---- phase 2: recompute Ab + gather A[send]; write BOTH output halves ------
__global__ __launch_bounds__(192, 6) void k_node2(
    const float* __restrict__ pos, const float* __restrict__ shifts,
    const float* __restrict__ Wemb, const float* __restrict__ Wrad,
    const float* __restrict__ War, const float* __restrict__ Wmem,
    const int* __restrict__ species, const int* __restrict__ eidx,
    const int* __restrict__ offs, const int* __restrict__ order,
    const uint4* __restrict__ Abf4, const float* __restrict__ chi,
    float* __restrict__ out, int N)
{
  __shared__ float wrad_s[256];
  __shared__ float war_s[64];
  __shared__ float wm_s[288];     // [d][r][b] stride-72
  __shared__ float wemb_s[12];
  __shared__ float Bsh[360];
  __shared__ __align__(16) float est[TILE*RS];
  int t = threadIdx.x, n = blockIdx.x;
  for (int i = t; i < 256; i += 192) wrad_s[i] = Wrad[i];
  for (int i = t; i < 256; i += 192) { int d = i>>6, rm = i&63; wm_s[d*72+rm] = Wmem[i]; }
  if (t < 64) war_s[t] = War[t];
  if (t < 12) wemb_s[t] = Wemb[t];
  for (int i = t; i < 360; i += 192) Bsh[i] = 0.0f;
  int l = t / 9, c = t - l*9;
  bool act = t < 180;
  int ll = act ? l : 0, cc = act ? c : 0;
  int tt = act ? t : 0;
  int dgl = act ? d_DEGS[ll] : 0;
  float mlt = act ? d_MULTI[ll] : 0.0f;
  float pnx = pos[n*3+0], pny = pos[n*3+1], pnz = pos[n*3+2];
  int zr = species[n];
  __syncthreads();                 // wemb_s ready
  float er0 = wemb_s[zr*3+0], er1 = wemb_s[zr*3+1], er2 = wemb_s[zr*3+2];
  int start = offs[n], end = offs[n+1];
  float Ab[8] = {0,0,0,0,0,0,0,0};
  float Sb[8] = {0,0,0,0,0,0,0,0};
  float AR[8] = {0,0,0,0,0,0,0,0};
  for (int tb = start; tb < end; tb += TILE) {
    int cnt = min(TILE, end - tb);
    fill_est(est, order, eidx, pos, shifts, species, war_s, wrad_s, wemb_s,
             tb, cnt, t, pnx, pny, pnz, er0, er1, er2);
    // depth-1 pipelined consumption (gather for next edge in flight)
    int s0 = __float_as_int(est[69]);
    uint4 q_c = Abf4[(size_t)s0*180 + tt];
    float ch_c = chi[s0*9 + cc];
    for (int j = 0; j < cnt; j++) {
      uint4 q = q_c; float ch = ch_c;
      if (j + 1 < cnt) {
        int sn = __float_as_int(est[(j+1)*RS + 69]);
        q_c = Abf4[(size_t)sn*180 + tt];
        ch_c = chi[sn*9 + cc];
      }
      const float* eb = est + j*RS;
      float p = eb[40+ll] * eb[60+cc];
      float pch = p * ch;
      const float4* gw4 = reinterpret_cast<const float4*>(eb + dgl*8);
      float4 g0 = gw4[0], g1 = gw4[1];
      Ab[0] += p*g0.x; Ab[1] += p*g0.y; Ab[2] += p*g0.z; Ab[3] += p*g0.w;
      Ab[4] += p*g1.x; Ab[5] += p*g1.y; Ab[6] += p*g1.z; Ab[7] += p*g1.w;
      Sb[0] += pch*g0.x; Sb[1] += pch*g0.y; Sb[2] += pch*g0.z; Sb[3] += pch*g0.w;
      Sb[4] += pch*g1.x; Sb[5] += pch*g1.y; Sb[6] += pch*g1.z; Sb[7] += pch*g1.w;
      const float4* fr4 = reinterpret_cast<const float4*>(eb + 32);
      float4 f0 = fr4[0], f1 = fr4[1];
      float a0 = __uint_as_float(q.x << 16), a1 = __uint_as_float(q.x & 0xffff0000u);
      float a2 = __uint_as_float(q.y << 16), a3 = __uint_as_float(q.y & 0xffff0000u);
      float a4 = __uint_as_float(q.z << 16), a5 = __uint_as_float(q.z & 0xffff0000u);
      float a6 = __uint_as_float(q.w << 16), a7 = __uint_as_float(q.w & 0xffff0000u);
      AR[0] += a0*f0.x; AR[1] += a1*f0.y; AR[2] += a2*f0.z; AR[3] += a3*f0.w;
      AR[4] += a4*f1.x; AR[5] += a5*f1.y; AR[6] += a6*f1.z; AR[7] += a7*f1.w;
    }
  }
  // ---- B0 from recomputed Ab (bit-identical to k_nodeA's) ------------------
  __syncthreads();     // est consumers done; Bsh zeros visible
  if (act) {
    if (l == 0) {
      #pragma unroll
      for (int b = 0; b < 8; b++) Bsh[b*45 + c] = Ab[b];
    }
    int kk = 1 + dgl;
    #pragma unroll
    for (int b = 0; b < 8; b++) atomicAdd(&Bsh[b*45 + kk*9 + c], mlt*Ab[b]*Ab[b]);
  }
  __syncthreads();
  for (int i = t; i < 360; i += 192)
    out[((size_t)n*360 + i)*2] = Bsh[i];          // B0 half
  __syncthreads();
  for (int i = t; i < 360; i += 192) Bsh[i] = 0.0f;
  __syncthreads();
  // ---- newA = (AR + Sb)*norm + mem(Ab); B1 ---------------------------------
  if (act) {
    const float* wmp = wm_s + dgl*72;
    float newA[8];
    #pragma unroll
    for (int b = 0; b < 8; b++) {
      float mem = 0.0f;
      #pragma unroll
      for (int r = 0; r < 8; r++) mem += Ab[r] * wmp[r*8+b];
      newA[b] = (AR[b] + Sb[b])*MPNORM + mem;
    }
    if (l == 0) {
      #pragma unroll
      for (int b = 0; b < 8; b++) Bsh[b*45 + c] = newA[b];
    }
    int kk = 1 + dgl;
    #pragma unroll
    for (int b = 0; b < 8; b++) atomicAdd(&Bsh[b*45 + kk*9 + c], mlt*newA[b]*newA[b]);
  }
  __syncthreads();
  for (int i = t; i < 360; i += 192)
    out[((size_t)n*360 + i)*2 + 1] = Bsh[i];      // B1 half
}

extern "C" void kernel_launch(void* const* d_in, const int* in_sizes, int n_in,
                              void* d_out, int out_size, void* d_ws, size_t ws_size,
                              hipStream_t stream) {
  const float* pos    = (const float*)d_in[0];
  const float* shifts = (const float*)d_in[1];
  const float* Wemb   = (const float*)d_in[2];
  const float* Wrad   = (const float*)d_in[3];
  const float* Wmem   = (const float*)d_in[4];
  const float* War    = (const float*)d_in[5];
  const float* Wchi   = (const float*)d_in[6];
  const int* species = (const int*)d_in[7];
  const int* eidx    = (const int*)d_in[8];
  float* out = (float*)d_out;
  int N = in_sizes[7];
  int E = in_sizes[8] / 2;

  char* base = (char*)d_ws;
  size_t off = 0;
  uint4* Abf4  = (uint4*)(base + off); off += (size_t)N*180*16;   // 5.76 MB
  float* chi   = (float*)(base + off); off += (size_t)N*9*4;
  int* offs    = (int*)(base + off);   off += (size_t)(N+1)*4;
  int* order   = (int*)(base + off);   off += (size_t)E*4;
  int* counts  = (int*)(base + off);   off += (size_t)N*4;
  int* cursor  = (int*)(base + off);   off += (size_t)N*4;

  hipMemsetAsync(counts, 0, (size_t)N*2*4, stream);   // counts + cursor
  int eb = (E + 255) / 256;
  k_count<<<eb, 256, 0, stream>>>(eidx, counts, E);
  k_scan<<<1, 256, 0, stream>>>(counts, offs, N);
  k_fill<<<eb, 256, 0, stream>>>(eidx, offs, cursor, order, E);
  k_nodeA<<<N, 192, 0, stream>>>(pos, shifts, Wemb, Wrad, War, Wchi, species,
                                 eidx, offs, order, Abf4, chi, N);
  k_node2<<<N, 192, 0, stream>>>(pos, shifts, Wemb, Wrad, War, Wmem, species,
                                 eidx, offs, order, Abf4, chi, out, N);
}